// Round 1
// baseline (214.717 us; speedup 1.0000x reference)
//
#include <hip/hip_runtime.h>

// Problem constants (from reference)
#define B_     256
#define M_     64
#define T_     1200
#define FT_    10
#define K_     17
#define PAD_   8
#define POOLK_ 75
#define POOLS_ 15
#define TP_    76            // pooled length
#define NSEG_  80            // T_/POOLS_ segments of 15
#define FEAT_  (FT_*TP_)     // 760
#define ROWS_  4             // rows (b*M+m) per block
#define NTHR_  320           // 4 rows * 80 segments, 5 waves
#define XLEN_  (T_ + 2*PAD_) // 1216

__global__ __launch_bounds__(NTHR_, 4)
void ChannelScorer_Distributed_39024072851482_kernel(
    const float* __restrict__ x,      // (B,1,M,T) -> row-major (B*M, T)
    const float* __restrict__ conv_w, // (FT,1,K) = 170
    const float* __restrict__ conv_b, // (FT,)
    const float* __restrict__ lin_w,  // (M, FEAT)
    const float* __restrict__ lin_b,  // (M,)
    float* __restrict__ out)          // (B,M,1) -> 16384
{
    __shared__ float xs[ROWS_][XLEN_];     // 4 padded rows: 19456 B
    __shared__ float S[ROWS_][FT_*NSEG_];  // 4*800 segment sums: 12800 B
    __shared__ float wsm[FT_*K_];          // 170
    __shared__ float bsm[FT_];             // 10
    __shared__ float red[NTHR_];           // block reduction scratch

    const int tid = threadIdx.x;
    const int r0  = blockIdx.x * ROWS_;    // first row of this block

    // ---- stage 4 x-rows into LDS (zero-padded by 8 on both sides) ----
    #pragma unroll
    for (int rl = 0; rl < ROWS_; ++rl) {
        const float4* xr = (const float4*)(x + (size_t)(r0 + rl) * T_); // 16B aligned
        if (tid < T_/4)   // 300 float4 per row
            *(float4*)&xs[rl][PAD_ + 4*tid] = xr[tid];
    }
    if (tid < ROWS_ * 2 * PAD_) {          // 64 threads zero the pads
        const int rl = tid >> 4;
        const int j  = tid & 15;
        xs[rl][(j < PAD_) ? j : (T_ + j)] = 0.f;  // 0..7 and 1208..1215
    }
    if (tid < FT_*K_) wsm[tid] = conv_w[tid];
    if (tid < FT_)    bsm[tid] = conv_b[tid];
    __syncthreads();

    // ---- conv + square + segment-sum: thread = (row_local, segment), all 10 filters ----
    const int rl = tid / NSEG_;            // 0..3
    const int g  = tid - rl * NSEG_;       // 0..79
    {
        // load the 31-sample window ONCE, reuse across all 10 filters
        float xv[POOLS_ + K_ - 1];
        const int base = POOLS_ * g;
        #pragma unroll
        for (int j = 0; j < POOLS_ + K_ - 1; ++j) xv[j] = xs[rl][base + j];

        #pragma unroll 1                   // keep code compact; xv stays live in VGPRs
        for (int f = 0; f < FT_; ++f) {
            float w[K_];
            #pragma unroll
            for (int k = 0; k < K_; ++k) w[k] = wsm[f*K_ + k]; // wave-uniform: broadcast
            const float bf = bsm[f];
            float seg = 0.f;
            #pragma unroll
            for (int j = 0; j < POOLS_; ++j) {
                float acc = bf;
                #pragma unroll
                for (int k = 0; k < K_; ++k)
                    acc = fmaf(xv[j + k], w[k], acc);
                seg = fmaf(acc, acc, seg);
            }
            S[rl][f*NSEG_ + g] = seg;      // consecutive lanes -> consecutive addrs
        }
    }
    __syncthreads();

    // ---- pool(5 segs) -> log -> dot with lin_w[m,:] ----
    float partial = 0.f;
    {
        const int m = (r0 + rl) & (M_ - 1);
        const float* lw = lin_w + (size_t)m * FEAT_;
        #pragma unroll 1
        for (int it = 0; it < (FEAT_ + NSEG_ - 1) / NSEG_; ++it) { // 10 iters
            const int i = g + it * NSEG_;
            if (i < FEAT_) {
                const int f = i / TP_;     // 0..9
                const int p = i - f * TP_; // 0..75
                const float* Sp = &S[rl][f*NSEG_ + p];
                float v = (Sp[0] + Sp[1] + Sp[2] + Sp[3] + Sp[4]) * (1.0f / POOLK_);
                v = fmaxf(v, 1e-10f);
                partial = fmaf(__logf(v), lw[i], partial);
            }
        }
    }

    // ---- per-row reduction over the 80-thread group ----
    red[tid] = partial;
    __syncthreads();
    if (g < 40) red[tid] += red[tid + 40];
    __syncthreads();
    if (g < 20) red[tid] += red[tid + 20];
    __syncthreads();
    if (g < 10) red[tid] += red[tid + 10];
    __syncthreads();
    if (g < 5)  red[tid] += red[tid + 5];
    __syncthreads();
    if (g == 0) {
        const int row = r0 + rl;
        out[row] = red[tid] + red[tid+1] + red[tid+2] + red[tid+3] + red[tid+4]
                 + lin_b[row & (M_ - 1)];
    }
}

extern "C" void kernel_launch(void* const* d_in, const int* in_sizes, int n_in,
                              void* d_out, int out_size, void* d_ws, size_t ws_size,
                              hipStream_t stream) {
    const float* x      = (const float*)d_in[0];
    const float* conv_w = (const float*)d_in[1];
    const float* conv_b = (const float*)d_in[2];
    const float* lin_w  = (const float*)d_in[3];
    const float* lin_b  = (const float*)d_in[4];
    float* out = (float*)d_out;

    dim3 grid((B_ * M_) / ROWS_);   // 4096 blocks
    dim3 block(NTHR_);              // 320 threads = 5 waves
    ChannelScorer_Distributed_39024072851482_kernel<<<grid, block, 0, stream>>>(
        x, conv_w, conv_b, lin_w, lin_b, out);
}

// Round 2
// 182.722 us; speedup vs baseline: 1.1751x; 1.1751x over previous
//
#include <hip/hip_runtime.h>

// Problem constants (from reference)
#define B_     256
#define M_     64
#define T_     1200
#define FT_    10
#define K_     17
#define PAD_   8
#define POOLK_ 75
#define POOLS_ 15
#define TP_    76            // pooled length
#define NSEG_  80            // T_/POOLS_ segments of 15
#define NPAIR_ (FT_*NSEG_)   // 800
#define FEAT_  (FT_*TP_)     // 760
#define XLEN_  (T_ + 2*PAD_) // 1216

__global__ __launch_bounds__(256, 4)
void ChannelScorer_Distributed_39024072851482_kernel(
    const float* __restrict__ x,      // (B,1,M,T) -> row-major (B*M, T)
    const float* __restrict__ conv_w, // (FT,1,K) = 170
    const float* __restrict__ conv_b, // (FT,)
    const float* __restrict__ lin_w,  // (M, FEAT)
    const float* __restrict__ lin_b,  // (M,)
    float* __restrict__ out)          // (B,M,1) -> 16384
{
    __shared__ float xs[XLEN_];      // 1216 padded row
    __shared__ float wsm[FT_*K_];    // 170
    __shared__ float bsm[FT_];       // 10
    __shared__ float S[NPAIR_];      // 800 segment sums of squared conv
    __shared__ float red[4];
    // total ~8.8 KB -> 8 blocks/CU (wave-capped), same shell as round 0

    const int row = blockIdx.x;      // b*M_+m
    const int m   = row & (M_-1);
    const int tid = threadIdx.x;

    // ---- stage x row into LDS (padded with zeros) ----
    if (tid < PAD_)      xs[tid] = 0.f;
    if (tid >= 256-PAD_) xs[tid + (T_ + PAD_ - (256-PAD_))] = 0.f; // 1208..1215
    {
        const float4* xr = (const float4*)(x + (size_t)row * T_); // 16B aligned
        for (int i = tid; i < T_/4; i += 256)
            *(float4*)&xs[PAD_ + 4*i] = xr[i];
    }
    for (int i = tid; i < FT_*K_; i += 256) wsm[i] = conv_w[i];
    if (tid < FT_) bsm[tid] = conv_b[tid];
    __syncthreads();

    // ---- conv + square + segment-sum ----
    // thread = (filter-group, segment): fg0 -> f 0..3, fg1 -> f 4..6, fg2 -> f 7..9
    // xv[31] loaded ONCE per thread, reused across the group's filters.
    if (tid < 3*NSEG_) {             // 240 active; wave3 lanes 48-63 skip uniformly
        const int fg = tid / NSEG_;  // 0..2 (g-major: waves are fg-pure or near)
        const int g  = tid - fg*NSEG_;
        const int f0 = (fg == 0) ? 0 : (fg == 1 ? 4 : 7);
        const int f1 = (fg == 0) ? 4 : (fg == 1 ? 7 : 10);

        float xv[POOLS_ + K_ - 1];   // 31 values, stays live in VGPRs
        const int base = POOLS_ * g;
        #pragma unroll
        for (int j = 0; j < POOLS_ + K_ - 1; ++j) xv[j] = xs[base + j];

        #pragma unroll 1
        for (int f = f0; f < f1; ++f) {
            float w[K_];
            #pragma unroll
            for (int k = 0; k < K_; ++k) w[k] = wsm[f*K_ + k]; // wave-uniform broadcast
            const float bf = bsm[f];
            float seg = 0.f;
            #pragma unroll
            for (int j = 0; j < POOLS_; ++j) {
                float acc = bf;
                #pragma unroll
                for (int k = 0; k < K_; ++k)
                    acc = fmaf(xv[j + k], w[k], acc);
                seg = fmaf(acc, acc, seg);
            }
            S[f*NSEG_ + g] = seg;    // consecutive lanes -> consecutive addrs
        }
    }
    __syncthreads();

    // ---- pooled -> log -> dot with lin_w[m,:]  (round-0 epilogue, verbatim) ----
    float partial = 0.f;
    const float* lw = lin_w + (size_t)m * FEAT_;
    for (int i = tid; i < FEAT_; i += 256) {
        const int f = i / TP_;            // 0..9
        const int p = i - f * TP_;        // 0..75
        const float* Sp = &S[f*NSEG_ + p];
        float v = (Sp[0] + Sp[1] + Sp[2] + Sp[3] + Sp[4]) * (1.0f/POOLK_);
        v = fmaxf(v, 1e-10f);
        partial = fmaf(__logf(v), lw[i], partial);
    }

    // ---- block reduction ----
    #pragma unroll
    for (int off = 32; off > 0; off >>= 1)
        partial += __shfl_down(partial, off, 64);
    const int wave = tid >> 6, lane = tid & 63;
    if (lane == 0) red[wave] = partial;
    __syncthreads();
    if (tid == 0)
        out[row] = red[0] + red[1] + red[2] + red[3] + lin_b[m];
}

extern "C" void kernel_launch(void* const* d_in, const int* in_sizes, int n_in,
                              void* d_out, int out_size, void* d_ws, size_t ws_size,
                              hipStream_t stream) {
    const float* x      = (const float*)d_in[0];
    const float* conv_w = (const float*)d_in[1];
    const float* conv_b = (const float*)d_in[2];
    const float* lin_w  = (const float*)d_in[3];
    const float* lin_b  = (const float*)d_in[4];
    float* out = (float*)d_out;

    dim3 grid(B_ * M_);             // 16384 blocks, 1 row each
    dim3 block(256);                // 4 waves
    ChannelScorer_Distributed_39024072851482_kernel<<<grid, block, 0, stream>>>(
        x, conv_w, conv_b, lin_w, lin_b, out);
}

// Round 3
// 174.408 us; speedup vs baseline: 1.2311x; 1.0477x over previous
//
#include <hip/hip_runtime.h>

// Problem constants (from reference)
#define B_     256
#define M_     64
#define T_     1200
#define FT_    10
#define K_     17
#define PAD_   8
#define POOLK_ 75
#define POOLS_ 15
#define TP_    76            // pooled length
#define NSEG_  80            // T_/POOLS_ segments of 15
#define NPAIR_ (FT_*NSEG_)   // 800
#define FEAT_  (FT_*TP_)     // 760
#define XLEN_  (T_ + 2*PAD_) // 1216
#define NTH_   3             // j-thirds per segment
#define NJ_    5             // conv outputs per third
#define XV_    (NJ_ + K_ - 1) // 21-sample window per thread

__global__ __launch_bounds__(256, 4)
void ChannelScorer_Distributed_39024072851482_kernel(
    const float* __restrict__ x,      // (B,1,M,T) -> row-major (B*M, T)
    const float* __restrict__ conv_w, // (FT,1,K) = 170
    const float* __restrict__ conv_b, // (FT,)
    const float* __restrict__ lin_w,  // (M, FEAT)
    const float* __restrict__ lin_b,  // (M,)
    float* __restrict__ out)          // (B,M,1) -> 16384
{
    __shared__ float xs[XLEN_];          // 1216 padded row (4.9 KB)
    __shared__ float S3[NTH_][NPAIR_];   // per-third partial sums (9.6 KB)
    __shared__ float red[4];
    // ~14.5 KB -> 8 blocks/CU (wave-capped at 64 VGPR, 4 at 128)

    const int row = blockIdx.x;          // b*M_+m
    const int m   = row & (M_-1);
    const int tid = threadIdx.x;

    // ---- stage x row into LDS (padded with zeros) ----
    if (tid < PAD_)      xs[tid] = 0.f;
    if (tid >= 256-PAD_) xs[tid + (T_ + PAD_ - (256-PAD_))] = 0.f; // 1208..1215
    {
        const float4* xr = (const float4*)(x + (size_t)row * T_); // 16B aligned
        for (int i = tid; i < T_/4; i += 256)
            *(float4*)&xs[PAD_ + 4*i] = xr[i];
    }
    __syncthreads();

    // ---- conv + square + partial segment-sum ----
    // thread = (third tau, segment g); each thread does ALL 10 filters on its
    // 5-output j-slice. f is block-uniform -> conv_w reads become s_load (SGPR),
    // every v_fmac then has w as its scalar operand. xv[21] is pinned in VGPRs.
    if (tid < NTH_*NSEG_) {              // 240 active
        const int tau = tid / NSEG_;     // 0..2
        const int g   = tid - tau*NSEG_; // 0..79
        const int base = POOLS_*g + NJ_*tau;

        float xv[XV_];
        #pragma unroll
        for (int u = 0; u < XV_; ++u) xv[u] = xs[base + u];
        // Opaque pin: compiler cannot rematerialize these LDS loads into the
        // inner loop (round 0/2 failure mode: VGPR=32, per-FMA ds_read).
        #pragma unroll
        for (int u = 0; u < XV_; ++u) asm volatile("" : "+v"(xv[u]));

        #pragma unroll 1
        for (int f = 0; f < FT_; ++f) {
            float w[K_];
            #pragma unroll
            for (int k = 0; k < K_; ++k) w[k] = conv_w[f*K_ + k]; // uniform -> s_load
            const float bf = conv_b[f];
            float part = 0.f;
            #pragma unroll
            for (int jj = 0; jj < NJ_; ++jj) {
                float acc = bf;
                #pragma unroll
                for (int k = 0; k < K_; ++k)
                    acc = fmaf(xv[jj + k], w[k], acc);
                part = fmaf(acc, acc, part);
            }
            S3[tau][f*NSEG_ + g] = part; // consecutive lanes -> consecutive addrs
        }
    }
    __syncthreads();

    // ---- combine thirds in place: S3[0][i] = sum_tau S3[tau][i] ----
    for (int i = tid; i < NPAIR_; i += 256)
        S3[0][i] = S3[0][i] + S3[1][i] + S3[2][i];
    __syncthreads();

    // ---- pool(5 segs) -> log -> dot with lin_w[m,:] ----
    float partial = 0.f;
    const float* lw = lin_w + (size_t)m * FEAT_;
    for (int i = tid; i < FEAT_; i += 256) {
        const int f = i / TP_;            // 0..9
        const int p = i - f * TP_;        // 0..75
        const float* Sp = &S3[0][f*NSEG_ + p];
        float v = (Sp[0] + Sp[1] + Sp[2] + Sp[3] + Sp[4]) * (1.0f/POOLK_);
        v = fmaxf(v, 1e-10f);
        partial = fmaf(__logf(v), lw[i], partial);
    }

    // ---- block reduction ----
    #pragma unroll
    for (int off = 32; off > 0; off >>= 1)
        partial += __shfl_down(partial, off, 64);
    const int wave = tid >> 6, lane = tid & 63;
    if (lane == 0) red[wave] = partial;
    __syncthreads();
    if (tid == 0)
        out[row] = red[0] + red[1] + red[2] + red[3] + lin_b[m];
}

extern "C" void kernel_launch(void* const* d_in, const int* in_sizes, int n_in,
                              void* d_out, int out_size, void* d_ws, size_t ws_size,
                              hipStream_t stream) {
    const float* x      = (const float*)d_in[0];
    const float* conv_w = (const float*)d_in[1];
    const float* conv_b = (const float*)d_in[2];
    const float* lin_w  = (const float*)d_in[3];
    const float* lin_b  = (const float*)d_in[4];
    float* out = (float*)d_out;

    dim3 grid(B_ * M_);             // 16384 blocks, 1 row each
    dim3 block(256);                // 4 waves
    ChannelScorer_Distributed_39024072851482_kernel<<<grid, block, 0, stream>>>(
        x, conv_w, conv_b, lin_w, lin_b, out);
}